// Round 4
// baseline (372.763 us; speedup 1.0000x reference)
//
#include <hip/hip_runtime.h>
#include <math.h>

// Problem constants: B=4, S=1024, DIM=1280, H=16, HD=80
// Inputs fp32 (confirmed: runtime probe took the fp32 path in r3).
// OUTPUT IS FP32 (reference returns fp32; r2/r3 failed by writing bf16
// shorts into the fp32 buffer -> stride-2 scramble + zero tail = 0.1487).
#define SCALE_F 0.11180339887498949f   // 80^-0.5
#define HDP 96                          // HD padded to multiple of 32 for QK^T

typedef short  short8  __attribute__((ext_vector_type(8)));
typedef short  short4v __attribute__((ext_vector_type(4)));
typedef float  f32x4   __attribute__((ext_vector_type(4)));
typedef __bf16 bf16x8  __attribute__((ext_vector_type(8)));

__device__ __forceinline__ float bf2f(short s) {
  union { unsigned u; float f; } v;
  v.u = ((unsigned)(unsigned short)s) << 16;
  return v.f;
}
// fp32 -> bf16 (RNE via hardware conversion)
__device__ __forceinline__ short f2b(float f) {
  __bf16 h = (__bf16)f;
  return __builtin_bit_cast(short, h);
}
__device__ __forceinline__ bool probe_is_bf16(const unsigned* probe) {
  return (probe[1] & 0xFFFFu) != 0u;
}

// ROCm clang versions differ on whether the gfx950 bf16 MFMA builtin takes
// <8 x short> or <8 x __bf16>. Expression-SFINAE: use whichever typechecks.
template <typename V>
__device__ __forceinline__ auto mfma_try(V a, V b, f32x4 c, int)
    -> decltype(__builtin_amdgcn_mfma_f32_16x16x32_bf16(a, b, c, 0, 0, 0)) {
  return __builtin_amdgcn_mfma_f32_16x16x32_bf16(a, b, c, 0, 0, 0);
}
template <typename V>
__device__ __forceinline__ f32x4 mfma_try(V a, V b, f32x4 c, long) {
  return __builtin_amdgcn_mfma_f32_16x16x32_bf16(
      __builtin_bit_cast(bf16x8, a), __builtin_bit_cast(bf16x8, b), c, 0, 0, 0);
}
__device__ __forceinline__ f32x4 MFMA(short8 a, short8 b, f32x4 c) {
  return mfma_try(a, b, c, 0);
}

// ------------------------------------------------------- canonicalize: x->bf16
// n = 5,242,880 elements; 8 per thread; grid exact.
__global__ __launch_bounds__(256) void cvt_x_kernel(
    const void* __restrict__ xin, short* __restrict__ xout,
    const unsigned* __restrict__ probe) {
  bool isb = probe_is_bf16(probe);
  size_t i = ((size_t)blockIdx.x * 256 + threadIdx.x) * 8;
  if (isb) {
    *(short8*)&xout[i] = *(const short8*)((const short*)xin + i);
  } else {
    const float* f = (const float*)xin + i;
    float4 a0 = *(const float4*)f;
    float4 a1 = *(const float4*)(f + 4);
    short8 sv;
    sv[0] = f2b(a0.x); sv[1] = f2b(a0.y); sv[2] = f2b(a0.z); sv[3] = f2b(a0.w);
    sv[4] = f2b(a1.x); sv[5] = f2b(a1.y); sv[6] = f2b(a1.z); sv[7] = f2b(a1.w);
    *(short8*)&xout[i] = sv;
  }
}

// --------------------------------------------- canonicalize: small vecs -> f32
__global__ __launch_bounds__(256) void cvt_f32_kernel(
    const void* __restrict__ in, float* __restrict__ out, int n,
    const unsigned* __restrict__ probe) {
  bool isb = probe_is_bf16(probe);
  int i = (blockIdx.x * 256 + threadIdx.x) * 4;
  if (i >= n) return;
  if (isb) {
    short4v v = *(const short4v*)((const short*)in + i);
    float4 o;
    o.x = bf2f(v[0]); o.y = bf2f(v[1]); o.z = bf2f(v[2]); o.w = bf2f(v[3]);
    *(float4*)&out[i] = o;
  } else {
    *(float4*)&out[i] = *(const float4*)((const float*)in + i);
  }
}

// ---------------------------------------------------------------- transpose
// out[n][k] = bf16(in[k][n]); in is R x C row-major (fp32 or bf16), out C x R.
__global__ __launch_bounds__(256) void transpose_kernel(
    const void* __restrict__ in, short* __restrict__ out, int R, int C,
    const unsigned* __restrict__ probe) {
  bool isb = probe_is_bf16(probe);
  __shared__ float tile[32][33];
  int t = threadIdx.x;
  int bx = blockIdx.x;  // over C
  int by = blockIdx.y;  // over R
  int r = t >> 3, c4 = (t & 7) * 4;
  size_t idx = (size_t)(by * 32 + r) * C + bx * 32 + c4;
  if (isb) {
    short4v v = *(const short4v*)((const short*)in + idx);
    tile[r][c4 + 0] = bf2f(v[0]);
    tile[r][c4 + 1] = bf2f(v[1]);
    tile[r][c4 + 2] = bf2f(v[2]);
    tile[r][c4 + 3] = bf2f(v[3]);
  } else {
    float4 v = *(const float4*)((const float*)in + idx);
    tile[r][c4 + 0] = v.x;
    tile[r][c4 + 1] = v.y;
    tile[r][c4 + 2] = v.z;
    tile[r][c4 + 3] = v.w;
  }
  __syncthreads();
  int rr = t >> 3, k4 = (t & 7) * 4;
  short4v o;
  o[0] = f2b(tile[k4 + 0][rr]);
  o[1] = f2b(tile[k4 + 1][rr]);
  o[2] = f2b(tile[k4 + 2][rr]);
  o[3] = f2b(tile[k4 + 3][rr]);
  *(short4v*)&out[(size_t)(bx * 32 + rr) * R + by * 32 + k4] = o;
}

// ---------------------------------------------------------------- QKV GEMM
// C(4096x3840) = Xb(4096x1280 bf16) @ Wqkv + bqkv, scattered into:
//   Qw,Kw: [bh][s][HDP] bf16 (d in [0,80), pad zeroed by rope kernel)
//   Vt:    [bh][d][s]  bf16 (transposed for PV B-fragments)
__global__ __launch_bounds__(256) void gemm_qkv_kernel(
    const short* __restrict__ X, const short* __restrict__ Wt,
    const float* __restrict__ bias, short* __restrict__ Qw,
    short* __restrict__ Kw, short* __restrict__ Vt) {
  const int K = 1280;
  __shared__ short As[128 * 40];
  __shared__ short Bs[128 * 40];
  int t = threadIdx.x;
  int bm = blockIdx.x / 30;
  int bn = blockIdx.x % 30;
  int m0 = bm * 128, n0 = bn * 128;
  int w = t >> 6, lane = t & 63;
  int wm = w & 1, wn = w >> 1;
  int quad = lane >> 4, l16 = lane & 15;
  f32x4 acc[4][4] = {};
  for (int k0 = 0; k0 < K; k0 += 32) {
    int row = t >> 2, ch = (t & 3) * 8;
    int row2 = row + 64;
    *(short8*)&As[row * 40 + ch]  = *(const short8*)&X[(size_t)(m0 + row) * K + k0 + ch];
    *(short8*)&As[row2 * 40 + ch] = *(const short8*)&X[(size_t)(m0 + row2) * K + k0 + ch];
    *(short8*)&Bs[row * 40 + ch]  = *(const short8*)&Wt[(size_t)(n0 + row) * K + k0 + ch];
    *(short8*)&Bs[row2 * 40 + ch] = *(const short8*)&Wt[(size_t)(n0 + row2) * K + k0 + ch];
    __syncthreads();
    short8 af[4], bfr[4];
#pragma unroll
    for (int mt = 0; mt < 4; mt++)
      af[mt] = *(const short8*)&As[(wm * 64 + mt * 16 + l16) * 40 + quad * 8];
#pragma unroll
    for (int nt = 0; nt < 4; nt++)
      bfr[nt] = *(const short8*)&Bs[(wn * 64 + nt * 16 + l16) * 40 + quad * 8];
#pragma unroll
    for (int mt = 0; mt < 4; mt++)
#pragma unroll
      for (int nt = 0; nt < 4; nt++)
        acc[mt][nt] = MFMA(af[mt], bfr[nt], acc[mt][nt]);
    __syncthreads();
  }
  // epilogue: bias + scatter
  float bv[4];
#pragma unroll
  for (int nt = 0; nt < 4; nt++) bv[nt] = bias[n0 + wn * 64 + nt * 16 + l16];
#pragma unroll
  for (int mt = 0; mt < 4; mt++) {
#pragma unroll
    for (int nt = 0; nt < 4; nt++) {
      int n = n0 + wn * 64 + nt * 16 + l16;
      int which = n / 1280;
      int rmod = n - which * 1280;
      int h = rmod / 80;
      int d = rmod - h * 80;
#pragma unroll
      for (int reg = 0; reg < 4; reg++) {
        int m = m0 + wm * 64 + mt * 16 + quad * 4 + reg;
        int b = m >> 10, s = m & 1023;
        int bh = b * 16 + h;
        short o = f2b(acc[mt][nt][reg] + bv[nt]);
        if (which == 0)
          Qw[((size_t)bh * 1024 + s) * HDP + d] = o;
        else if (which == 1)
          Kw[((size_t)bh * 1024 + s) * HDP + d] = o;
        else
          Vt[((size_t)bh * 80 + d) * 1024 + s] = o;
      }
    }
  }
}

// ---------------------------------------------------------------- RoPE
// In-place rope on Qw/Kw rows (bf16); lanes 40..55 zero the pad d=80..95.
__global__ __launch_bounds__(256) void rope_kernel(
    short* __restrict__ Qw, short* __restrict__ Kw,
    const float* __restrict__ cosb, const float* __restrict__ sinb) {
  int t = threadIdx.x;
  int w = t >> 6, lane = t & 63;
  int job = blockIdx.x * 4 + w;   // 64*1024*2 jobs
  int which = job & 1;
  int row = job >> 1;             // bh*1024 + s
  int s = row & 1023;
  short* ptr = (which ? Kw : Qw) + (size_t)row * HDP;
  if (lane < 40) {
    float p0 = bf2f(ptr[lane]);
    float p1 = bf2f(ptr[lane + 40]);
    float c0 = cosb[s * 80 + lane];
    float s0 = sinb[s * 80 + lane];
    float c1 = cosb[s * 80 + lane + 40];
    float s1 = sinb[s * 80 + lane + 40];
    ptr[lane] = f2b(p0 * c0 - p1 * s0);
    ptr[lane + 40] = f2b(p1 * c1 + p0 * s1);
  } else if (lane < 56) {
    ptr[40 + lane] = 0;  // d = 80..95
  }
}

// ---------------------------------------------------------------- attention
// One block per (bh, q-tile of 64). 4 waves, each owns 16 Q rows.
__global__ __launch_bounds__(256) void attn_kernel(
    const short* __restrict__ Qw, const short* __restrict__ Kw,
    const short* __restrict__ Vt, short* __restrict__ out) {
  __shared__ short Qs[64 * 104];        // 64 rows x 96 (pad to 104)
  __shared__ short Ps[4][2][16 * 72];   // per-wave P tile, double-buffered
  int t = threadIdx.x;
  int w = t >> 6, lane = t & 63;
  int quad = lane >> 4, l16 = lane & 15;
  int bh = blockIdx.x >> 4;
  int qt = blockIdx.x & 15;
  int q0 = qt * 64;
  // stage Q tile
  {
    int row = t >> 2;
    const short* src = Qw + ((size_t)bh * 1024 + q0 + row) * HDP;
#pragma unroll
    for (int i = 0; i < 3; i++) {
      int col = ((t & 3) + 4 * i) * 8;
      *(short8*)&Qs[row * 104 + col] = *(const short8*)&src[col];
    }
  }
  __syncthreads();
  short8 aq[3];
#pragma unroll
  for (int ks = 0; ks < 3; ks++)
    aq[ks] = *(const short8*)&Qs[(w * 16 + l16) * 104 + ks * 32 + quad * 8];
  f32x4 ofr[5] = {};
  float mrow[4], lrow[4];
#pragma unroll
  for (int r = 0; r < 4; r++) { mrow[r] = -INFINITY; lrow[r] = 0.f; }
  const short* Kb = Kw + (size_t)bh * 1024 * HDP;
  const short* Vb = Vt + (size_t)bh * 80 * 1024;
  for (int c = 0; c < 1024; c += 64) {
    // QK^T chunk: S(16x64) per wave
    short8 bk[4][3];
#pragma unroll
    for (int nt = 0; nt < 4; nt++)
#pragma unroll
      for (int ks = 0; ks < 3; ks++)
        bk[nt][ks] = *(const short8*)&Kb[(size_t)(c + nt * 16 + l16) * HDP + ks * 32 + quad * 8];
    f32x4 sf[4] = {};
#pragma unroll
    for (int ks = 0; ks < 3; ks++)
#pragma unroll
      for (int nt = 0; nt < 4; nt++)
        sf[nt] = MFMA(aq[ks], bk[nt][ks], sf[nt]);
    // online softmax (rows = quad*4+reg, replicated across the 16-lane quad)
    float mn[4];
#pragma unroll
    for (int r = 0; r < 4; r++) {
      float mx = -INFINITY;
#pragma unroll
      for (int nt = 0; nt < 4; nt++) {
        sf[nt][r] *= SCALE_F;
        mx = fmaxf(mx, sf[nt][r]);
      }
      mn[r] = mx;
    }
#pragma unroll
    for (int off = 1; off < 16; off <<= 1)
#pragma unroll
      for (int r = 0; r < 4; r++) mn[r] = fmaxf(mn[r], __shfl_xor(mn[r], off));
    float al[4], sum[4];
#pragma unroll
    for (int r = 0; r < 4; r++) {
      float mnew = fmaxf(mrow[r], mn[r]);
      al[r] = __expf(mrow[r] - mnew);
      mrow[r] = mnew;
      float sacc = 0.f;
#pragma unroll
      for (int nt = 0; nt < 4; nt++) {
        float p = __expf(sf[nt][r] - mnew);
        sf[nt][r] = p;
        sacc += p;
      }
      sum[r] = sacc;
    }
#pragma unroll
    for (int off = 1; off < 16; off <<= 1)
#pragma unroll
      for (int r = 0; r < 4; r++) sum[r] += __shfl_xor(sum[r], off);
#pragma unroll
    for (int r = 0; r < 4; r++) lrow[r] = lrow[r] * al[r] + sum[r];
    // P -> LDS (C-layout -> A-layout round trip), per-wave private buffer
    int pb = (c >> 6) & 1;
    short* Pw = &Ps[w][pb][0];
#pragma unroll
    for (int nt = 0; nt < 4; nt++)
#pragma unroll
      for (int r = 0; r < 4; r++)
        Pw[(quad * 4 + r) * 72 + nt * 16 + l16] = f2b(sf[nt][r]);
    // rescale O while P writes land
#pragma unroll
    for (int nt = 0; nt < 5; nt++)
#pragma unroll
      for (int r = 0; r < 4; r++) ofr[nt][r] *= al[r];
    __syncthreads();  // drain LDS writes before A-frag reads
    short8 ap[2];
#pragma unroll
    for (int ks = 0; ks < 2; ks++)
      ap[ks] = *(const short8*)&Pw[l16 * 72 + ks * 32 + quad * 8];
    short8 bvf[5][2];
#pragma unroll
    for (int nt = 0; nt < 5; nt++)
#pragma unroll
      for (int ks = 0; ks < 2; ks++)
        bvf[nt][ks] = *(const short8*)&Vb[(size_t)(nt * 16 + l16) * 1024 + c + ks * 32 + quad * 8];
#pragma unroll
    for (int ks = 0; ks < 2; ks++)
#pragma unroll
      for (int nt = 0; nt < 5; nt++)
        ofr[nt] = MFMA(ap[ks], bvf[nt][ks], ofr[nt]);
  }
  // epilogue: normalize and write [b][s][h*80+d]
  float inv[4];
#pragma unroll
  for (int r = 0; r < 4; r++) inv[r] = 1.f / lrow[r];
  int b = bh >> 4, h = bh & 15;
#pragma unroll
  for (int nt = 0; nt < 5; nt++) {
    int d = nt * 16 + l16;
#pragma unroll
    for (int r = 0; r < 4; r++) {
      int s = q0 + w * 16 + quad * 4 + r;
      out[((size_t)(b * 1024 + s)) * 1280 + h * 80 + d] = f2b(ofr[nt][r] * inv[r]);
    }
  }
}

// ---------------------------------------------------------------- proj GEMM
// out(4096x1280 FP32) = At(bf16) @ Wproj + bproj (fp32 bias, fp32 store)
__global__ __launch_bounds__(256) void gemm_proj_kernel(
    const short* __restrict__ A, const short* __restrict__ Wt,
    const float* __restrict__ bias, float* __restrict__ out) {
  const int K = 1280;
  __shared__ short As[128 * 40];
  __shared__ short Bs[128 * 40];
  int t = threadIdx.x;
  int bm = blockIdx.x / 10;
  int bn = blockIdx.x % 10;
  int m0 = bm * 128, n0 = bn * 128;
  int w = t >> 6, lane = t & 63;
  int wm = w & 1, wn = w >> 1;
  int quad = lane >> 4, l16 = lane & 15;
  f32x4 acc[4][4] = {};
  for (int k0 = 0; k0 < K; k0 += 32) {
    int row = t >> 2, ch = (t & 3) * 8;
    int row2 = row + 64;
    *(short8*)&As[row * 40 + ch]  = *(const short8*)&A[(size_t)(m0 + row) * K + k0 + ch];
    *(short8*)&As[row2 * 40 + ch] = *(const short8*)&A[(size_t)(m0 + row2) * K + k0 + ch];
    *(short8*)&Bs[row * 40 + ch]  = *(const short8*)&Wt[(size_t)(n0 + row) * K + k0 + ch];
    *(short8*)&Bs[row2 * 40 + ch] = *(const short8*)&Wt[(size_t)(n0 + row2) * K + k0 + ch];
    __syncthreads();
    short8 af[4], bfr[4];
#pragma unroll
    for (int mt = 0; mt < 4; mt++)
      af[mt] = *(const short8*)&As[(wm * 64 + mt * 16 + l16) * 40 + quad * 8];
#pragma unroll
    for (int nt = 0; nt < 4; nt++)
      bfr[nt] = *(const short8*)&Bs[(wn * 64 + nt * 16 + l16) * 40 + quad * 8];
#pragma unroll
    for (int mt = 0; mt < 4; mt++)
#pragma unroll
      for (int nt = 0; nt < 4; nt++)
        acc[mt][nt] = MFMA(af[mt], bfr[nt], acc[mt][nt]);
    __syncthreads();
  }
  float bv[4];
#pragma unroll
  for (int nt = 0; nt < 4; nt++) bv[nt] = bias[n0 + wn * 64 + nt * 16 + l16];
#pragma unroll
  for (int mt = 0; mt < 4; mt++) {
#pragma unroll
    for (int nt = 0; nt < 4; nt++) {
      int n = n0 + wn * 64 + nt * 16 + l16;
#pragma unroll
      for (int reg = 0; reg < 4; reg++) {
        int m = m0 + wm * 64 + mt * 16 + quad * 4 + reg;
        out[(size_t)m * 1280 + n] = acc[mt][nt][reg] + bv[nt];  // FP32 store
      }
    }
  }
}

extern "C" void kernel_launch(void* const* d_in, const int* in_sizes, int n_in,
                              void* d_out, int out_size, void* d_ws, size_t ws_size,
                              hipStream_t stream) {
  const void* x        = d_in[0];
  const void* rope_cos = d_in[1];
  const void* rope_sin = d_in[2];
  const void* Wqkv     = d_in[3];
  const void* bqkv     = d_in[4];
  const void* Wproj    = d_in[5];
  const void* bproj    = d_in[6];
  const unsigned* probe = (const unsigned*)rope_cos;
  char* ws = (char*)d_ws;
  short* Wt1 = (short*)(ws + 0);          // 1280*3840*2 = 9,830,400
  short* Wt2 = (short*)(ws + 9830400);    // 1280*1280*2 = 3,276,800
  short* Qw  = (short*)(ws + 13107200);   // 64*1024*96*2 = 12,582,912
  short* Kw  = (short*)(ws + 25690112);   // 12,582,912
  short* Vt  = (short*)(ws + 38273024);   // 64*1024*80*2 = 10,485,760
  // Xb and At share a slot: Xb is dead after gemm_qkv, At born in attn.
  short* Xb  = (short*)(ws + 48758784);   // 4096*1280*2 = 10,485,760
  short* At  = (short*)(ws + 48758784);
  float* cosf_ = (float*)(ws + 59244544); // 1024*80*4 = 327,680
  float* sinf_ = (float*)(ws + 59572224); // 327,680
  float* bqf   = (float*)(ws + 59899904); // 3840*4 = 15,360
  float* bpf   = (float*)(ws + 59915264); // 1280*4 = 5,120   (end 59,920,384)

  cvt_x_kernel<<<2560, 256, 0, stream>>>(x, Xb, probe);
  cvt_f32_kernel<<<80, 256, 0, stream>>>(rope_cos, cosf_, 81920, probe);
  cvt_f32_kernel<<<80, 256, 0, stream>>>(rope_sin, sinf_, 81920, probe);
  cvt_f32_kernel<<<4, 256, 0, stream>>>(bqkv, bqf, 3840, probe);
  cvt_f32_kernel<<<2, 256, 0, stream>>>(bproj, bpf, 1280, probe);
  transpose_kernel<<<dim3(3840 / 32, 1280 / 32), 256, 0, stream>>>(Wqkv, Wt1, 1280, 3840, probe);
  transpose_kernel<<<dim3(1280 / 32, 1280 / 32), 256, 0, stream>>>(Wproj, Wt2, 1280, 1280, probe);
  gemm_qkv_kernel<<<32 * 30, 256, 0, stream>>>(Xb, Wt1, bqf, Qw, Kw, Vt);
  rope_kernel<<<32768, 256, 0, stream>>>(Qw, Kw, cosf_, sinf_);
  attn_kernel<<<1024, 256, 0, stream>>>(Qw, Kw, Vt, At);
  gemm_proj_kernel<<<32 * 10, 256, 0, stream>>>(At, Wt2, bpf, (float*)d_out);
}

// Round 5
// 314.960 us; speedup vs baseline: 1.1835x; 1.1835x over previous
//
#include <hip/hip_runtime.h>
#include <math.h>

// Problem constants: B=4, S=1024, DIM=1280, H=16, HD=80
// Inputs fp32; OUTPUT IS FP32 (r4 passed with this contract).
#define SCALE_F 0.11180339887498949f   // 80^-0.5
#define HDP 96                          // HD padded to multiple of 32 for QK^T

typedef short  short8  __attribute__((ext_vector_type(8)));
typedef short  short4v __attribute__((ext_vector_type(4)));
typedef float  f32x4   __attribute__((ext_vector_type(4)));
typedef __bf16 bf16x8  __attribute__((ext_vector_type(8)));

__device__ __forceinline__ float bf2f(short s) {
  union { unsigned u; float f; } v;
  v.u = ((unsigned)(unsigned short)s) << 16;
  return v.f;
}
// fp32 -> bf16 (RNE via hardware conversion)
__device__ __forceinline__ short f2b(float f) {
  __bf16 h = (__bf16)f;
  return __builtin_bit_cast(short, h);
}
__device__ __forceinline__ bool probe_is_bf16(const unsigned* probe) {
  return (probe[1] & 0xFFFFu) != 0u;
}

// ROCm clang versions differ on whether the gfx950 bf16 MFMA builtin takes
// <8 x short> or <8 x __bf16>. Expression-SFINAE: use whichever typechecks.
template <typename V>
__device__ __forceinline__ auto mfma_try(V a, V b, f32x4 c, int)
    -> decltype(__builtin_amdgcn_mfma_f32_16x16x32_bf16(a, b, c, 0, 0, 0)) {
  return __builtin_amdgcn_mfma_f32_16x16x32_bf16(a, b, c, 0, 0, 0);
}
template <typename V>
__device__ __forceinline__ f32x4 mfma_try(V a, V b, f32x4 c, long) {
  return __builtin_amdgcn_mfma_f32_16x16x32_bf16(
      __builtin_bit_cast(bf16x8, a), __builtin_bit_cast(bf16x8, b), c, 0, 0, 0);
}
__device__ __forceinline__ f32x4 MFMA(short8 a, short8 b, f32x4 c) {
  return mfma_try(a, b, c, 0);
}

// ------------------------------------------------------- canonicalize: x->bf16
__global__ __launch_bounds__(256) void cvt_x_kernel(
    const void* __restrict__ xin, short* __restrict__ xout,
    const unsigned* __restrict__ probe) {
  bool isb = probe_is_bf16(probe);
  size_t i = ((size_t)blockIdx.x * 256 + threadIdx.x) * 8;
  if (isb) {
    *(short8*)&xout[i] = *(const short8*)((const short*)xin + i);
  } else {
    const float* f = (const float*)xin + i;
    float4 a0 = *(const float4*)f;
    float4 a1 = *(const float4*)(f + 4);
    short8 sv;
    sv[0] = f2b(a0.x); sv[1] = f2b(a0.y); sv[2] = f2b(a0.z); sv[3] = f2b(a0.w);
    sv[4] = f2b(a1.x); sv[5] = f2b(a1.y); sv[6] = f2b(a1.z); sv[7] = f2b(a1.w);
    *(short8*)&xout[i] = sv;
  }
}

// --------------------------------------------- canonicalize: small vecs -> f32
__global__ __launch_bounds__(256) void cvt_f32_kernel(
    const void* __restrict__ in, float* __restrict__ out, int n,
    const unsigned* __restrict__ probe) {
  bool isb = probe_is_bf16(probe);
  int i = (blockIdx.x * 256 + threadIdx.x) * 4;
  if (i >= n) return;
  if (isb) {
    short4v v = *(const short4v*)((const short*)in + i);
    float4 o;
    o.x = bf2f(v[0]); o.y = bf2f(v[1]); o.z = bf2f(v[2]); o.w = bf2f(v[3]);
    *(float4*)&out[i] = o;
  } else {
    *(float4*)&out[i] = *(const float4*)((const float*)in + i);
  }
}

// ---------------------------------------------------------------- transpose
__global__ __launch_bounds__(256) void transpose_kernel(
    const void* __restrict__ in, short* __restrict__ out, int R, int C,
    const unsigned* __restrict__ probe) {
  bool isb = probe_is_bf16(probe);
  __shared__ float tile[32][33];
  int t = threadIdx.x;
  int bx = blockIdx.x;  // over C
  int by = blockIdx.y;  // over R
  int r = t >> 3, c4 = (t & 7) * 4;
  size_t idx = (size_t)(by * 32 + r) * C + bx * 32 + c4;
  if (isb) {
    short4v v = *(const short4v*)((const short*)in + idx);
    tile[r][c4 + 0] = bf2f(v[0]);
    tile[r][c4 + 1] = bf2f(v[1]);
    tile[r][c4 + 2] = bf2f(v[2]);
    tile[r][c4 + 3] = bf2f(v[3]);
  } else {
    float4 v = *(const float4*)((const float*)in + idx);
    tile[r][c4 + 0] = v.x;
    tile[r][c4 + 1] = v.y;
    tile[r][c4 + 2] = v.z;
    tile[r][c4 + 3] = v.w;
  }
  __syncthreads();
  int rr = t >> 3, k4 = (t & 7) * 4;
  short4v o;
  o[0] = f2b(tile[k4 + 0][rr]);
  o[1] = f2b(tile[k4 + 1][rr]);
  o[2] = f2b(tile[k4 + 2][rr]);
  o[3] = f2b(tile[k4 + 3][rr]);
  *(short4v*)&out[(size_t)(bx * 32 + rr) * R + by * 32 + k4] = o;
}

// ---------------------------------------------------------------- QKV GEMM
__global__ __launch_bounds__(256) void gemm_qkv_kernel(
    const short* __restrict__ X, const short* __restrict__ Wt,
    const float* __restrict__ bias, short* __restrict__ Qw,
    short* __restrict__ Kw, short* __restrict__ Vt) {
  const int K = 1280;
  __shared__ short As[128 * 40];
  __shared__ short Bs[128 * 40];
  int t = threadIdx.x;
  int bm = blockIdx.x / 30;
  int bn = blockIdx.x % 30;
  int m0 = bm * 128, n0 = bn * 128;
  int w = t >> 6, lane = t & 63;
  int wm = w & 1, wn = w >> 1;
  int quad = lane >> 4, l16 = lane & 15;
  f32x4 acc[4][4] = {};
  for (int k0 = 0; k0 < K; k0 += 32) {
    int row = t >> 2, ch = (t & 3) * 8;
    int row2 = row + 64;
    *(short8*)&As[row * 40 + ch]  = *(const short8*)&X[(size_t)(m0 + row) * K + k0 + ch];
    *(short8*)&As[row2 * 40 + ch] = *(const short8*)&X[(size_t)(m0 + row2) * K + k0 + ch];
    *(short8*)&Bs[row * 40 + ch]  = *(const short8*)&Wt[(size_t)(n0 + row) * K + k0 + ch];
    *(short8*)&Bs[row2 * 40 + ch] = *(const short8*)&Wt[(size_t)(n0 + row2) * K + k0 + ch];
    __syncthreads();
    short8 af[4], bfr[4];
#pragma unroll
    for (int mt = 0; mt < 4; mt++)
      af[mt] = *(const short8*)&As[(wm * 64 + mt * 16 + l16) * 40 + quad * 8];
#pragma unroll
    for (int nt = 0; nt < 4; nt++)
      bfr[nt] = *(const short8*)&Bs[(wn * 64 + nt * 16 + l16) * 40 + quad * 8];
#pragma unroll
    for (int mt = 0; mt < 4; mt++)
#pragma unroll
      for (int nt = 0; nt < 4; nt++)
        acc[mt][nt] = MFMA(af[mt], bfr[nt], acc[mt][nt]);
    __syncthreads();
  }
  float bv[4];
#pragma unroll
  for (int nt = 0; nt < 4; nt++) bv[nt] = bias[n0 + wn * 64 + nt * 16 + l16];
#pragma unroll
  for (int mt = 0; mt < 4; mt++) {
#pragma unroll
    for (int nt = 0; nt < 4; nt++) {
      int n = n0 + wn * 64 + nt * 16 + l16;
      int which = n / 1280;
      int rmod = n - which * 1280;
      int h = rmod / 80;
      int d = rmod - h * 80;
#pragma unroll
      for (int reg = 0; reg < 4; reg++) {
        int m = m0 + wm * 64 + mt * 16 + quad * 4 + reg;
        int b = m >> 10, s = m & 1023;
        int bh = b * 16 + h;
        short o = f2b(acc[mt][nt][reg] + bv[nt]);
        if (which == 0)
          Qw[((size_t)bh * 1024 + s) * HDP + d] = o;
        else if (which == 1)
          Kw[((size_t)bh * 1024 + s) * HDP + d] = o;
        else
          Vt[((size_t)bh * 80 + d) * 1024 + s] = o;
      }
    }
  }
}

// ---------------------------------------------------------------- RoPE
__global__ __launch_bounds__(256) void rope_kernel(
    short* __restrict__ Qw, short* __restrict__ Kw,
    const float* __restrict__ cosb, const float* __restrict__ sinb) {
  int t = threadIdx.x;
  int w = t >> 6, lane = t & 63;
  int job = blockIdx.x * 4 + w;   // 64*1024*2 jobs
  int which = job & 1;
  int row = job >> 1;             // bh*1024 + s
  int s = row & 1023;
  short* ptr = (which ? Kw : Qw) + (size_t)row * HDP;
  if (lane < 40) {
    float p0 = bf2f(ptr[lane]);
    float p1 = bf2f(ptr[lane + 40]);
    float c0 = cosb[s * 80 + lane];
    float s0 = sinb[s * 80 + lane];
    float c1 = cosb[s * 80 + lane + 40];
    float s1 = sinb[s * 80 + lane + 40];
    ptr[lane] = f2b(p0 * c0 - p1 * s0);
    ptr[lane + 40] = f2b(p1 * c1 + p0 * s1);
  } else if (lane < 56) {
    ptr[40 + lane] = 0;  // d = 80..95
  }
}

// ---------------------------------------------------------------- attention
// One block per (bh, q-tile of 64). 4 waves, each owns 16 Q rows.
// K/V staged cooperatively in LDS (shared by the 4 waves), register-prefetch
// pipeline hides global latency. Q fragments loaded once from global.
__global__ __launch_bounds__(256) void attn_kernel(
    const short* __restrict__ Qw, const short* __restrict__ Kw,
    const short* __restrict__ Vt, short* __restrict__ out) {
  __shared__ short Klds[64 * 104];   // [s_local][d], pad 96->104 (2-way free)
  __shared__ short Vlds[80 * 72];    // [d][s_local], pad 64->72 (2-way free)
  __shared__ short Ps[4][16 * 72];   // per-wave P tile (in-order DS per wave)
  int t = threadIdx.x;
  int w = t >> 6, lane = t & 63;
  int quad = lane >> 4, l16 = lane & 15;
  int bh = blockIdx.x >> 4;
  int qt = blockIdx.x & 15;
  int q0 = qt * 64;
  const short* Kb = Kw + (size_t)bh * 1024 * HDP;
  const short* Vb = Vt + (size_t)bh * 80 * 1024;

  // Q fragments straight from global (one-time)
  short8 aq[3];
  {
    const short* qrow = Qw + ((size_t)bh * 1024 + q0 + w * 16 + l16) * HDP;
#pragma unroll
    for (int ks = 0; ks < 3; ks++)
      aq[ks] = *(const short8*)&qrow[ks * 32 + quad * 8];
  }

  // cooperative staging: K chunk = 768 b128 pieces, V chunk = 640 b128 pieces
  short8 kreg[3], vreg[3];
#define PREFETCH(c)                                                        \
  {                                                                        \
    _Pragma("unroll") for (int i = 0; i < 3; i++) {                        \
      int idx = i * 256 + t;                                               \
      int row = idx / 12, col = (idx % 12) * 8;                            \
      kreg[i] = *(const short8*)&Kb[(size_t)((c) + row) * HDP + col];      \
    }                                                                      \
    _Pragma("unroll") for (int i = 0; i < 3; i++) {                        \
      int idx = i * 256 + t;                                               \
      if (idx < 640) {                                                     \
        int d = idx >> 3, s0 = (idx & 7) * 8;                              \
        vreg[i] = *(const short8*)&Vb[(size_t)d * 1024 + (c) + s0];        \
      }                                                                    \
    }                                                                      \
  }
#define STORE_LDS()                                                        \
  {                                                                        \
    _Pragma("unroll") for (int i = 0; i < 3; i++) {                        \
      int idx = i * 256 + t;                                               \
      int row = idx / 12, col = (idx % 12) * 8;                            \
      *(short8*)&Klds[row * 104 + col] = kreg[i];                          \
    }                                                                      \
    _Pragma("unroll") for (int i = 0; i < 3; i++) {                        \
      int idx = i * 256 + t;                                               \
      if (idx < 640) {                                                     \
        int d = idx >> 3, s0 = (idx & 7) * 8;                              \
        *(short8*)&Vlds[d * 72 + s0] = vreg[i];                            \
      }                                                                    \
    }                                                                      \
  }

  PREFETCH(0);
  STORE_LDS();
  __syncthreads();

  f32x4 ofr[5] = {};
  float mrow[4], lrow[4];
#pragma unroll
  for (int r = 0; r < 4; r++) { mrow[r] = -INFINITY; lrow[r] = 0.f; }

  for (int c = 0; c < 1024; c += 64) {
    if (c + 64 < 1024) PREFETCH(c + 64);   // global loads overlap compute
    // QK^T chunk from LDS: S(16x64) per wave
    f32x4 sf[4] = {};
#pragma unroll
    for (int nt = 0; nt < 4; nt++) {
      short8 bk0 = *(const short8*)&Klds[(nt * 16 + l16) * 104 + 0 * 32 + quad * 8];
      short8 bk1 = *(const short8*)&Klds[(nt * 16 + l16) * 104 + 1 * 32 + quad * 8];
      short8 bk2 = *(const short8*)&Klds[(nt * 16 + l16) * 104 + 2 * 32 + quad * 8];
      sf[nt] = MFMA(aq[0], bk0, sf[nt]);
      sf[nt] = MFMA(aq[1], bk1, sf[nt]);
      sf[nt] = MFMA(aq[2], bk2, sf[nt]);
    }
    // online softmax (rows = quad*4+reg, replicated across the 16-lane quad)
    float mn[4];
#pragma unroll
    for (int r = 0; r < 4; r++) {
      float mx = -INFINITY;
#pragma unroll
      for (int nt = 0; nt < 4; nt++) {
        sf[nt][r] *= SCALE_F;
        mx = fmaxf(mx, sf[nt][r]);
      }
      mn[r] = mx;
    }
#pragma unroll
    for (int off = 1; off < 16; off <<= 1)
#pragma unroll
      for (int r = 0; r < 4; r++) mn[r] = fmaxf(mn[r], __shfl_xor(mn[r], off));
    float al[4], sum[4];
#pragma unroll
    for (int r = 0; r < 4; r++) {
      float mnew = fmaxf(mrow[r], mn[r]);
      al[r] = __expf(mrow[r] - mnew);
      mrow[r] = mnew;
      float sacc = 0.f;
#pragma unroll
      for (int nt = 0; nt < 4; nt++) {
        float p = __expf(sf[nt][r] - mnew);
        sf[nt][r] = p;
        sacc += p;
      }
      sum[r] = sacc;
    }
#pragma unroll
    for (int off = 1; off < 16; off <<= 1)
#pragma unroll
      for (int r = 0; r < 4; r++) sum[r] += __shfl_xor(sum[r], off);
#pragma unroll
    for (int r = 0; r < 4; r++) lrow[r] = lrow[r] * al[r] + sum[r];
    // P -> LDS (C-layout -> A-layout), per-wave buffer; DS is in-order per wave
    short* Pw = &Ps[w][0];
#pragma unroll
    for (int nt = 0; nt < 4; nt++)
#pragma unroll
      for (int r = 0; r < 4; r++)
        Pw[(quad * 4 + r) * 72 + nt * 16 + l16] = f2b(sf[nt][r]);
    // rescale O while P writes land
#pragma unroll
    for (int nt = 0; nt < 5; nt++)
#pragma unroll
      for (int r = 0; r < 4; r++) ofr[nt][r] *= al[r];
    __threadfence_block();  // lgkmcnt drain (r2==r3 proved sufficient)
    short8 ap[2];
#pragma unroll
    for (int ks = 0; ks < 2; ks++)
      ap[ks] = *(const short8*)&Pw[l16 * 72 + ks * 32 + quad * 8];
    // PV from LDS V tile
#pragma unroll
    for (int nt = 0; nt < 5; nt++) {
      short8 bv0 = *(const short8*)&Vlds[(nt * 16 + l16) * 72 + 0 * 32 + quad * 8];
      short8 bv1 = *(const short8*)&Vlds[(nt * 16 + l16) * 72 + 1 * 32 + quad * 8];
      ofr[nt] = MFMA(ap[0], bv0, ofr[nt]);
      ofr[nt] = MFMA(ap[1], bv1, ofr[nt]);
    }
    __syncthreads();          // all waves done reading K/V LDS
    if (c + 64 < 1024) {
      STORE_LDS();            // publish next chunk
      __syncthreads();
    }
  }
  // epilogue: normalize and write [b][s][h*80+d]
  float inv[4];
#pragma unroll
  for (int r = 0; r < 4; r++) inv[r] = 1.f / lrow[r];
  int b = bh >> 4, h = bh & 15;
#pragma unroll
  for (int nt = 0; nt < 5; nt++) {
    int d = nt * 16 + l16;
#pragma unroll
    for (int r = 0; r < 4; r++) {
      int s = q0 + w * 16 + quad * 4 + r;
      out[((size_t)(b * 1024 + s)) * 1280 + h * 80 + d] = f2b(ofr[nt][r] * inv[r]);
    }
  }
}

// ---------------------------------------------------------------- proj GEMM
// out(4096x1280 FP32) = At(bf16) @ Wproj + bproj (fp32 bias, fp32 store)
__global__ __launch_bounds__(256) void gemm_proj_kernel(
    const short* __restrict__ A, const short* __restrict__ Wt,
    const float* __restrict__ bias, float* __restrict__ out) {
  const int K = 1280;
  __shared__ short As[128 * 40];
  __shared__ short Bs[128 * 40];
  int t = threadIdx.x;
  int bm = blockIdx.x / 10;
  int bn = blockIdx.x % 10;
  int m0 = bm * 128, n0 = bn * 128;
  int w = t >> 6, lane = t & 63;
  int wm = w & 1, wn = w >> 1;
  int quad = lane >> 4, l16 = lane & 15;
  f32x4 acc[4][4] = {};
  for (int k0 = 0; k0 < K; k0 += 32) {
    int row = t >> 2, ch = (t & 3) * 8;
    int row2 = row + 64;
    *(short8*)&As[row * 40 + ch]  = *(const short8*)&A[(size_t)(m0 + row) * K + k0 + ch];
    *(short8*)&As[row2 * 40 + ch] = *(const short8*)&A[(size_t)(m0 + row2) * K + k0 + ch];
    *(short8*)&Bs[row * 40 + ch]  = *(const short8*)&Wt[(size_t)(n0 + row) * K + k0 + ch];
    *(short8*)&Bs[row2 * 40 + ch] = *(const short8*)&Wt[(size_t)(n0 + row2) * K + k0 + ch];
    __syncthreads();
    short8 af[4], bfr[4];
#pragma unroll
    for (int mt = 0; mt < 4; mt++)
      af[mt] = *(const short8*)&As[(wm * 64 + mt * 16 + l16) * 40 + quad * 8];
#pragma unroll
    for (int nt = 0; nt < 4; nt++)
      bfr[nt] = *(const short8*)&Bs[(wn * 64 + nt * 16 + l16) * 40 + quad * 8];
#pragma unroll
    for (int mt = 0; mt < 4; mt++)
#pragma unroll
      for (int nt = 0; nt < 4; nt++)
        acc[mt][nt] = MFMA(af[mt], bfr[nt], acc[mt][nt]);
    __syncthreads();
  }
  float bv[4];
#pragma unroll
  for (int nt = 0; nt < 4; nt++) bv[nt] = bias[n0 + wn * 64 + nt * 16 + l16];
#pragma unroll
  for (int mt = 0; mt < 4; mt++) {
#pragma unroll
    for (int nt = 0; nt < 4; nt++) {
      int n = n0 + wn * 64 + nt * 16 + l16;
#pragma unroll
      for (int reg = 0; reg < 4; reg++) {
        int m = m0 + wm * 64 + mt * 16 + quad * 4 + reg;
        out[(size_t)m * 1280 + n] = acc[mt][nt][reg] + bv[nt];  // FP32 store
      }
    }
  }
}

extern "C" void kernel_launch(void* const* d_in, const int* in_sizes, int n_in,
                              void* d_out, int out_size, void* d_ws, size_t ws_size,
                              hipStream_t stream) {
  const void* x        = d_in[0];
  const void* rope_cos = d_in[1];
  const void* rope_sin = d_in[2];
  const void* Wqkv     = d_in[3];
  const void* bqkv     = d_in[4];
  const void* Wproj    = d_in[5];
  const void* bproj    = d_in[6];
  const unsigned* probe = (const unsigned*)rope_cos;
  char* ws = (char*)d_ws;
  short* Wt1 = (short*)(ws + 0);          // 1280*3840*2 = 9,830,400
  short* Wt2 = (short*)(ws + 9830400);    // 1280*1280*2 = 3,276,800
  short* Qw  = (short*)(ws + 13107200);   // 64*1024*96*2 = 12,582,912
  short* Kw  = (short*)(ws + 25690112);   // 12,582,912
  short* Vt  = (short*)(ws + 38273024);   // 64*1024*80*2 = 10,485,760
  short* Xb  = (short*)(ws + 48758784);   // 4096*1280*2 = 10,485,760
  short* At  = (short*)(ws + 48758784);   // aliases Xb (disjoint lifetimes)
  float* cosf_ = (float*)(ws + 59244544); // 1024*80*4 = 327,680
  float* sinf_ = (float*)(ws + 59572224); // 327,680
  float* bqf   = (float*)(ws + 59899904); // 3840*4 = 15,360
  float* bpf   = (float*)(ws + 59915264); // 1280*4 = 5,120

  cvt_x_kernel<<<2560, 256, 0, stream>>>(x, Xb, probe);
  cvt_f32_kernel<<<80, 256, 0, stream>>>(rope_cos, cosf_, 81920, probe);
  cvt_f32_kernel<<<80, 256, 0, stream>>>(rope_sin, sinf_, 81920, probe);
  cvt_f32_kernel<<<4, 256, 0, stream>>>(bqkv, bqf, 3840, probe);
  cvt_f32_kernel<<<2, 256, 0, stream>>>(bproj, bpf, 1280, probe);
  transpose_kernel<<<dim3(3840 / 32, 1280 / 32), 256, 0, stream>>>(Wqkv, Wt1, 1280, 3840, probe);
  transpose_kernel<<<dim3(1280 / 32, 1280 / 32), 256, 0, stream>>>(Wproj, Wt2, 1280, 1280, probe);
  gemm_qkv_kernel<<<32 * 30, 256, 0, stream>>>(Xb, Wt1, bqf, Qw, Kw, Vt);
  rope_kernel<<<32768, 256, 0, stream>>>(Qw, Kw, cosf_, sinf_);
  attn_kernel<<<1024, 256, 0, stream>>>(Qw, Kw, Vt, At);
  gemm_proj_kernel<<<32 * 10, 256, 0, stream>>>(At, Wt2, bpf, (float*)d_out);
}

// Round 6
// 305.741 us; speedup vs baseline: 1.2192x; 1.0302x over previous
//
#include <hip/hip_runtime.h>
#include <math.h>

// Problem constants: B=4, S=1024, DIM=1280, H=16, HD=80
// Inputs fp32 (runtime-probed); OUTPUT FP32. r4/r5 passed with this contract.
#define SCALE_F 0.11180339887498949f   // 80^-0.5
#define HDP 96                          // HD padded to multiple of 32 for QK^T

typedef short  short8  __attribute__((ext_vector_type(8)));
typedef short  short4v __attribute__((ext_vector_type(4)));
typedef float  f32x4   __attribute__((ext_vector_type(4)));
typedef __bf16 bf16x8  __attribute__((ext_vector_type(8)));

__device__ __forceinline__ float bf2f(short s) {
  union { unsigned u; float f; } v;
  v.u = ((unsigned)(unsigned short)s) << 16;
  return v.f;
}
__device__ __forceinline__ short f2b(float f) {
  __bf16 h = (__bf16)f;
  return __builtin_bit_cast(short, h);
}
__device__ __forceinline__ bool probe_is_bf16(const unsigned* probe) {
  return (probe[1] & 0xFFFFu) != 0u;
}
__device__ __forceinline__ float load_scalar(const void* p, int i, bool isb) {
  return isb ? bf2f(((const short*)p)[i]) : ((const float*)p)[i];
}

// async global->LDS DMA, 16B per lane; LDS dst = wave-uniform base + lane*16.
__device__ __forceinline__ void gl_lds16(const short* g, short* l) {
  __builtin_amdgcn_global_load_lds(
      (const __attribute__((address_space(1))) unsigned*)(uintptr_t)g,
      (__attribute__((address_space(3))) unsigned*)(unsigned)(uintptr_t)l,
      16, 0, 0);
}

template <typename V>
__device__ __forceinline__ auto mfma_try(V a, V b, f32x4 c, int)
    -> decltype(__builtin_amdgcn_mfma_f32_16x16x32_bf16(a, b, c, 0, 0, 0)) {
  return __builtin_amdgcn_mfma_f32_16x16x32_bf16(a, b, c, 0, 0, 0);
}
template <typename V>
__device__ __forceinline__ f32x4 mfma_try(V a, V b, f32x4 c, long) {
  return __builtin_amdgcn_mfma_f32_16x16x32_bf16(
      __builtin_bit_cast(bf16x8, a), __builtin_bit_cast(bf16x8, b), c, 0, 0, 0);
}
__device__ __forceinline__ f32x4 MFMA(short8 a, short8 b, f32x4 c) {
  return mfma_try(a, b, c, 0);
}

// ------------------------------------------------------- canonicalize: x->bf16
__global__ __launch_bounds__(256) void cvt_x_kernel(
    const void* __restrict__ xin, short* __restrict__ xout,
    const unsigned* __restrict__ probe) {
  bool isb = probe_is_bf16(probe);
  size_t i = ((size_t)blockIdx.x * 256 + threadIdx.x) * 8;
  if (isb) {
    *(short8*)&xout[i] = *(const short8*)((const short*)xin + i);
  } else {
    const float* f = (const float*)xin + i;
    float4 a0 = *(const float4*)f;
    float4 a1 = *(const float4*)(f + 4);
    short8 sv;
    sv[0] = f2b(a0.x); sv[1] = f2b(a0.y); sv[2] = f2b(a0.z); sv[3] = f2b(a0.w);
    sv[4] = f2b(a1.x); sv[5] = f2b(a1.y); sv[6] = f2b(a1.z); sv[7] = f2b(a1.w);
    *(short8*)&xout[i] = sv;
  }
}

// ---------------------------------------------------------------- transpose
__global__ __launch_bounds__(256) void transpose_kernel(
    const void* __restrict__ in, short* __restrict__ out, int R, int C,
    const unsigned* __restrict__ probe) {
  bool isb = probe_is_bf16(probe);
  __shared__ float tile[32][33];
  int t = threadIdx.x;
  int bx = blockIdx.x;  // over C
  int by = blockIdx.y;  // over R
  int r = t >> 3, c4 = (t & 7) * 4;
  size_t idx = (size_t)(by * 32 + r) * C + bx * 32 + c4;
  if (isb) {
    short4v v = *(const short4v*)((const short*)in + idx);
    tile[r][c4 + 0] = bf2f(v[0]);
    tile[r][c4 + 1] = bf2f(v[1]);
    tile[r][c4 + 2] = bf2f(v[2]);
    tile[r][c4 + 3] = bf2f(v[3]);
  } else {
    float4 v = *(const float4*)((const float*)in + idx);
    tile[r][c4 + 0] = v.x;
    tile[r][c4 + 1] = v.y;
    tile[r][c4 + 2] = v.z;
    tile[r][c4 + 3] = v.w;
  }
  __syncthreads();
  int rr = t >> 3, k4 = (t & 7) * 4;
  short4v o;
  o[0] = f2b(tile[k4 + 0][rr]);
  o[1] = f2b(tile[k4 + 1][rr]);
  o[2] = f2b(tile[k4 + 2][rr]);
  o[3] = f2b(tile[k4 + 3][rr]);
  *(short4v*)&out[(size_t)(bx * 32 + rr) * R + by * 32 + k4] = o;
}

// ---------------------------------------------------------------- QKV GEMM
// m97 structure: unpadded [128][32] LDS tiles, global_load_lds width=16
// staging (4 DMA/wave/k-iter), 2-barrier K-loop, 4x4 MFMA per wave.
__global__ __launch_bounds__(256) void gemm_qkv_kernel(
    const short* __restrict__ X, const short* __restrict__ Wt,
    const void* __restrict__ bias, const unsigned* __restrict__ probe,
    short* __restrict__ Qw, short* __restrict__ Kw, short* __restrict__ Vt) {
  const int K = 1280;
  __shared__ short As[128 * 32];
  __shared__ short Bs[128 * 32];
  int t = threadIdx.x;
  int bm = blockIdx.x / 30;
  int bn = blockIdx.x % 30;
  int m0 = bm * 128, n0 = bn * 128;
  int w = t >> 6, lane = t & 63;
  int wm = w & 1, wn = w >> 1;
  int quad = lane >> 4, l16 = lane & 15;
  // staging geometry: granule g in [0,512), 16B each; wave w covers g in
  // [w*128, w*128+128) via two DMA issues (64 lanes each).
  int g0 = w * 128 + lane;
  int g1 = g0 + 64;
  const short* Ag0 = X  + (size_t)(m0 + (g0 >> 2)) * K + (g0 & 3) * 8;
  const short* Ag1 = X  + (size_t)(m0 + (g1 >> 2)) * K + (g1 & 3) * 8;
  const short* Bg0 = Wt + (size_t)(n0 + (g0 >> 2)) * K + (g0 & 3) * 8;
  const short* Bg1 = Wt + (size_t)(n0 + (g1 >> 2)) * K + (g1 & 3) * 8;
  short* Al0 = As + w * 1024;        // (w*128 granules)*8 shorts
  short* Al1 = As + w * 1024 + 512;
  short* Bl0 = Bs + w * 1024;
  short* Bl1 = Bs + w * 1024 + 512;
  f32x4 acc[4][4] = {};
  for (int k0 = 0; k0 < K; k0 += 32) {
    gl_lds16(Ag0 + k0, Al0);
    gl_lds16(Ag1 + k0, Al1);
    gl_lds16(Bg0 + k0, Bl0);
    gl_lds16(Bg1 + k0, Bl1);
    __syncthreads();   // vmcnt(0) drain + barrier: DMA visible to all waves
    short8 af[4], bfr[4];
#pragma unroll
    for (int mt = 0; mt < 4; mt++)
      af[mt] = *(const short8*)&As[(wm * 64 + mt * 16 + l16) * 32 + quad * 8];
#pragma unroll
    for (int nt = 0; nt < 4; nt++)
      bfr[nt] = *(const short8*)&Bs[(wn * 64 + nt * 16 + l16) * 32 + quad * 8];
#pragma unroll
    for (int mt = 0; mt < 4; mt++)
#pragma unroll
      for (int nt = 0; nt < 4; nt++)
        acc[mt][nt] = MFMA(af[mt], bfr[nt], acc[mt][nt]);
    __syncthreads();   // all reads done before next DMA overwrites
  }
  // epilogue: bias (runtime dtype) + scatter
  bool isb = probe_is_bf16(probe);
  float bv[4];
#pragma unroll
  for (int nt = 0; nt < 4; nt++)
    bv[nt] = load_scalar(bias, n0 + wn * 64 + nt * 16 + l16, isb);
#pragma unroll
  for (int mt = 0; mt < 4; mt++) {
#pragma unroll
    for (int nt = 0; nt < 4; nt++) {
      int n = n0 + wn * 64 + nt * 16 + l16;
      int which = n / 1280;
      int rmod = n - which * 1280;
      int h = rmod / 80;
      int d = rmod - h * 80;
#pragma unroll
      for (int reg = 0; reg < 4; reg++) {
        int m = m0 + wm * 64 + mt * 16 + quad * 4 + reg;
        int b = m >> 10, s = m & 1023;
        int bh = b * 16 + h;
        short o = f2b(acc[mt][nt][reg] + bv[nt]);
        if (which == 0)
          Qw[((size_t)bh * 1024 + s) * HDP + d] = o;
        else if (which == 1)
          Kw[((size_t)bh * 1024 + s) * HDP + d] = o;
        else
          Vt[((size_t)bh * 80 + d) * 1024 + s] = o;
      }
    }
  }
}

// ---------------------------------------------------------------- RoPE
__global__ __launch_bounds__(256) void rope_kernel(
    short* __restrict__ Qw, short* __restrict__ Kw,
    const void* __restrict__ cosb, const void* __restrict__ sinb,
    const unsigned* __restrict__ probe) {
  bool isb = probe_is_bf16(probe);
  int t = threadIdx.x;
  int w = t >> 6, lane = t & 63;
  int job = blockIdx.x * 4 + w;   // 64*1024*2 jobs
  int which = job & 1;
  int row = job >> 1;             // bh*1024 + s
  int s = row & 1023;
  short* ptr = (which ? Kw : Qw) + (size_t)row * HDP;
  if (lane < 40) {
    float p0 = bf2f(ptr[lane]);
    float p1 = bf2f(ptr[lane + 40]);
    float c0 = load_scalar(cosb, s * 80 + lane, isb);
    float s0 = load_scalar(sinb, s * 80 + lane, isb);
    float c1 = load_scalar(cosb, s * 80 + lane + 40, isb);
    float s1 = load_scalar(sinb, s * 80 + lane + 40, isb);
    ptr[lane] = f2b(p0 * c0 - p1 * s0);
    ptr[lane + 40] = f2b(p1 * c1 + p0 * s1);
  } else if (lane < 56) {
    ptr[40 + lane] = 0;  // d = 80..95
  }
}

// ---------------------------------------------------------------- attention
// (unchanged from round 5 — staged K/V in LDS + register prefetch pipeline)
__global__ __launch_bounds__(256) void attn_kernel(
    const short* __restrict__ Qw, const short* __restrict__ Kw,
    const short* __restrict__ Vt, short* __restrict__ out) {
  __shared__ short Klds[64 * 104];   // [s_local][d], pad 96->104 (2-way free)
  __shared__ short Vlds[80 * 72];    // [d][s_local], pad 64->72 (2-way free)
  __shared__ short Ps[4][16 * 72];   // per-wave P tile (in-order DS per wave)
  int t = threadIdx.x;
  int w = t >> 6, lane = t & 63;
  int quad = lane >> 4, l16 = lane & 15;
  int bh = blockIdx.x >> 4;
  int qt = blockIdx.x & 15;
  int q0 = qt * 64;
  const short* Kb = Kw + (size_t)bh * 1024 * HDP;
  const short* Vb = Vt + (size_t)bh * 80 * 1024;

  short8 aq[3];
  {
    const short* qrow = Qw + ((size_t)bh * 1024 + q0 + w * 16 + l16) * HDP;
#pragma unroll
    for (int ks = 0; ks < 3; ks++)
      aq[ks] = *(const short8*)&qrow[ks * 32 + quad * 8];
  }

  short8 kreg[3], vreg[3];
#define PREFETCH(c)                                                        \
  {                                                                        \
    _Pragma("unroll") for (int i = 0; i < 3; i++) {                        \
      int idx = i * 256 + t;                                               \
      int row = idx / 12, col = (idx % 12) * 8;                            \
      kreg[i] = *(const short8*)&Kb[(size_t)((c) + row) * HDP + col];      \
    }                                                                      \
    _Pragma("unroll") for (int i = 0; i < 3; i++) {                        \
      int idx = i * 256 + t;                                               \
      if (idx < 640) {                                                     \
        int d = idx >> 3, s0 = (idx & 7) * 8;                              \
        vreg[i] = *(const short8*)&Vb[(size_t)d * 1024 + (c) + s0];        \
      }                                                                    \
    }                                                                      \
  }
#define STORE_LDS()                                                        \
  {                                                                        \
    _Pragma("unroll") for (int i = 0; i < 3; i++) {                        \
      int idx = i * 256 + t;                                               \
      int row = idx / 12, col = (idx % 12) * 8;                            \
      *(short8*)&Klds[row * 104 + col] = kreg[i];                          \
    }                                                                      \
    _Pragma("unroll") for (int i = 0; i < 3; i++) {                        \
      int idx = i * 256 + t;                                               \
      if (idx < 640) {                                                     \
        int d = idx >> 3, s0 = (idx & 7) * 8;                              \
        *(short8*)&Vlds[d * 72 + s0] = vreg[i];                            \
      }                                                                    \
    }                                                                      \
  }

  PREFETCH(0);
  STORE_LDS();
  __syncthreads();

  f32x4 ofr[5] = {};
  float mrow[4], lrow[4];
#pragma unroll
  for (int r = 0; r < 4; r++) { mrow[r] = -INFINITY; lrow[r] = 0.f; }

  for (int c = 0; c < 1024; c += 64) {
    if (c + 64 < 1024) PREFETCH(c + 64);
    f32x4 sf[4] = {};
#pragma unroll
    for (int nt = 0; nt < 4; nt++) {
      short8 bk0 = *(const short8*)&Klds[(nt * 16 + l16) * 104 + 0 * 32 + quad * 8];
      short8 bk1 = *(const short8*)&Klds[(nt * 16 + l16) * 104 + 1 * 32 + quad * 8];
      short8 bk2 = *(const short8*)&Klds[(nt * 16 + l16) * 104 + 2 * 32 + quad * 8];
      sf[nt] = MFMA(aq[0], bk0, sf[nt]);
      sf[nt] = MFMA(aq[1], bk1, sf[nt]);
      sf[nt] = MFMA(aq[2], bk2, sf[nt]);
    }
    float mn[4];
#pragma unroll
    for (int r = 0; r < 4; r++) {
      float mx = -INFINITY;
#pragma unroll
      for (int nt = 0; nt < 4; nt++) {
        sf[nt][r] *= SCALE_F;
        mx = fmaxf(mx, sf[nt][r]);
      }
      mn[r] = mx;
    }
#pragma unroll
    for (int off = 1; off < 16; off <<= 1)
#pragma unroll
      for (int r = 0; r < 4; r++) mn[r] = fmaxf(mn[r], __shfl_xor(mn[r], off));
    float al[4], sum[4];
#pragma unroll
    for (int r = 0; r < 4; r++) {
      float mnew = fmaxf(mrow[r], mn[r]);
      al[r] = __expf(mrow[r] - mnew);
      mrow[r] = mnew;
      float sacc = 0.f;
#pragma unroll
      for (int nt = 0; nt < 4; nt++) {
        float p = __expf(sf[nt][r] - mnew);
        sf[nt][r] = p;
        sacc += p;
      }
      sum[r] = sacc;
    }
#pragma unroll
    for (int off = 1; off < 16; off <<= 1)
#pragma unroll
      for (int r = 0; r < 4; r++) sum[r] += __shfl_xor(sum[r], off);
#pragma unroll
    for (int r = 0; r < 4; r++) lrow[r] = lrow[r] * al[r] + sum[r];
    short* Pw = &Ps[w][0];
#pragma unroll
    for (int nt = 0; nt < 4; nt++)
#pragma unroll
      for (int r = 0; r < 4; r++)
        Pw[(quad * 4 + r) * 72 + nt * 16 + l16] = f2b(sf[nt][r]);
#pragma unroll
    for (int nt = 0; nt < 5; nt++)
#pragma unroll
      for (int r = 0; r < 4; r++) ofr[nt][r] *= al[r];
    __threadfence_block();
    short8 ap[2];
#pragma unroll
    for (int ks = 0; ks < 2; ks++)
      ap[ks] = *(const short8*)&Pw[l16 * 72 + ks * 32 + quad * 8];
#pragma unroll
    for (int nt = 0; nt < 5; nt++) {
      short8 bv0 = *(const short8*)&Vlds[(nt * 16 + l16) * 72 + 0 * 32 + quad * 8];
      short8 bv1 = *(const short8*)&Vlds[(nt * 16 + l16) * 72 + 1 * 32 + quad * 8];
      ofr[nt] = MFMA(ap[0], bv0, ofr[nt]);
      ofr[nt] = MFMA(ap[1], bv1, ofr[nt]);
    }
    __syncthreads();
    if (c + 64 < 1024) {
      STORE_LDS();
      __syncthreads();
    }
  }
  float inv[4];
#pragma unroll
  for (int r = 0; r < 4; r++) inv[r] = 1.f / lrow[r];
  int b = bh >> 4, h = bh & 15;
#pragma unroll
  for (int nt = 0; nt < 5; nt++) {
    int d = nt * 16 + l16;
#pragma unroll
    for (int r = 0; r < 4; r++) {
      int s = q0 + w * 16 + quad * 4 + r;
      out[((size_t)(b * 1024 + s)) * 1280 + h * 80 + d] = f2b(ofr[nt][r] * inv[r]);
    }
  }
}

// ---------------------------------------------------------------- proj GEMM
// m97 structure; out(4096x1280 FP32) = At(bf16) @ Wproj + bproj
__global__ __launch_bounds__(256) void gemm_proj_kernel(
    const short* __restrict__ A, const short* __restrict__ Wt,
    const void* __restrict__ bias, const unsigned* __restrict__ probe,
    float* __restrict__ out) {
  const int K = 1280;
  __shared__ short As[128 * 32];
  __shared__ short Bs[128 * 32];
  int t = threadIdx.x;
  int bm = blockIdx.x / 10;
  int bn = blockIdx.x % 10;
  int m0 = bm * 128, n0 = bn * 128;
  int w = t >> 6, lane = t & 63;
  int wm = w & 1, wn = w >> 1;
  int quad = lane >> 4, l16 = lane & 15;
  int g0 = w * 128 + lane;
  int g1 = g0 + 64;
  const short* Ag0 = A  + (size_t)(m0 + (g0 >> 2)) * K + (g0 & 3) * 8;
  const short* Ag1 = A  + (size_t)(m0 + (g1 >> 2)) * K + (g1 & 3) * 8;
  const short* Bg0 = Wt + (size_t)(n0 + (g0 >> 2)) * K + (g0 & 3) * 8;
  const short* Bg1 = Wt + (size_t)(n0 + (g1 >> 2)) * K + (g1 & 3) * 8;
  short* Al0 = As + w * 1024;
  short* Al1 = As + w * 1024 + 512;
  short* Bl0 = Bs + w * 1024;
  short* Bl1 = Bs + w * 1024 + 512;
  f32x4 acc[4][4] = {};
  for (int k0 = 0; k0 < K; k0 += 32) {
    gl_lds16(Ag0 + k0, Al0);
    gl_lds16(Ag1 + k0, Al1);
    gl_lds16(Bg0 + k0, Bl0);
    gl_lds16(Bg1 + k0, Bl1);
    __syncthreads();
    short8 af[4], bfr[4];
#pragma unroll
    for (int mt = 0; mt < 4; mt++)
      af[mt] = *(const short8*)&As[(wm * 64 + mt * 16 + l16) * 32 + quad * 8];
#pragma unroll
    for (int nt = 0; nt < 4; nt++)
      bfr[nt] = *(const short8*)&Bs[(wn * 64 + nt * 16 + l16) * 32 + quad * 8];
#pragma unroll
    for (int mt = 0; mt < 4; mt++)
#pragma unroll
      for (int nt = 0; nt < 4; nt++)
        acc[mt][nt] = MFMA(af[mt], bfr[nt], acc[mt][nt]);
    __syncthreads();
  }
  bool isb = probe_is_bf16(probe);
  float bv[4];
#pragma unroll
  for (int nt = 0; nt < 4; nt++)
    bv[nt] = load_scalar(bias, n0 + wn * 64 + nt * 16 + l16, isb);
#pragma unroll
  for (int mt = 0; mt < 4; mt++) {
#pragma unroll
    for (int nt = 0; nt < 4; nt++) {
      int n = n0 + wn * 64 + nt * 16 + l16;
#pragma unroll
      for (int reg = 0; reg < 4; reg++) {
        int m = m0 + wm * 64 + mt * 16 + quad * 4 + reg;
        out[(size_t)m * 1280 + n] = acc[mt][nt][reg] + bv[nt];  // FP32 store
      }
    }
  }
}

extern "C" void kernel_launch(void* const* d_in, const int* in_sizes, int n_in,
                              void* d_out, int out_size, void* d_ws, size_t ws_size,
                              hipStream_t stream) {
  const void* x        = d_in[0];
  const void* rope_cos = d_in[1];
  const void* rope_sin = d_in[2];
  const void* Wqkv     = d_in[3];
  const void* bqkv     = d_in[4];
  const void* Wproj    = d_in[5];
  const void* bproj    = d_in[6];
  const unsigned* probe = (const unsigned*)rope_cos;
  char* ws = (char*)d_ws;
  short* Wt1 = (short*)(ws + 0);          // 1280*3840*2 = 9,830,400
  short* Wt2 = (short*)(ws + 9830400);    // 1280*1280*2 = 3,276,800
  short* Qw  = (short*)(ws + 13107200);   // 64*1024*96*2 = 12,582,912
  short* Kw  = (short*)(ws + 25690112);   // 12,582,912
  short* Vt  = (short*)(ws + 38273024);   // 64*1024*80*2 = 10,485,760
  short* Xb  = (short*)(ws + 48758784);   // 4096*1280*2 = 10,485,760
  short* At  = (short*)(ws + 48758784);   // aliases Xb (disjoint lifetimes)

  cvt_x_kernel<<<2560, 256, 0, stream>>>(x, Xb, probe);
  transpose_kernel<<<dim3(3840 / 32, 1280 / 32), 256, 0, stream>>>(Wqkv, Wt1, 1280, 3840, probe);
  transpose_kernel<<<dim3(1280 / 32, 1280 / 32), 256, 0, stream>>>(Wproj, Wt2, 1280, 1280, probe);
  gemm_qkv_kernel<<<32 * 30, 256, 0, stream>>>(Xb, Wt1, bqkv, probe, Qw, Kw, Vt);
  rope_kernel<<<32768, 256, 0, stream>>>(Qw, Kw, rope_cos, rope_sin, probe);
  attn_kernel<<<1024, 256, 0, stream>>>(Qw, Kw, Vt, At);
  gemm_proj_kernel<<<32 * 10, 256, 0, stream>>>(At, Wt2, bproj, probe, (float*)d_out);
}

// Round 7
// 285.551 us; speedup vs baseline: 1.3054x; 1.0707x over previous
//
#include <hip/hip_runtime.h>
#include <math.h>

// Problem constants: B=4, S=1024, DIM=1280, H=16, HD=80
// Inputs fp32 (runtime-probed); OUTPUT FP32.
#define SCALE_F 0.11180339887498949f   // 80^-0.5
#define HDP 96                          // HD padded to multiple of 32 for QK^T

typedef short  short8  __attribute__((ext_vector_type(8)));
typedef short  short4v __attribute__((ext_vector_type(4)));
typedef float  f32x4   __attribute__((ext_vector_type(4)));
typedef __bf16 bf16x8  __attribute__((ext_vector_type(8)));

__device__ __forceinline__ float bf2f(short s) {
  union { unsigned u; float f; } v;
  v.u = ((unsigned)(unsigned short)s) << 16;
  return v.f;
}
__device__ __forceinline__ short f2b(float f) {
  __bf16 h = (__bf16)f;
  return __builtin_bit_cast(short, h);
}
__device__ __forceinline__ bool probe_is_bf16(const unsigned* probe) {
  return (probe[1] & 0xFFFFu) != 0u;
}
__device__ __forceinline__ float load_scalar(const void* p, int i, bool isb) {
  return isb ? bf2f(((const short*)p)[i]) : ((const float*)p)[i];
}

template <typename V>
__device__ __forceinline__ auto mfma_try(V a, V b, f32x4 c, int)
    -> decltype(__builtin_amdgcn_mfma_f32_16x16x32_bf16(a, b, c, 0, 0, 0)) {
  return __builtin_amdgcn_mfma_f32_16x16x32_bf16(a, b, c, 0, 0, 0);
}
template <typename V>
__device__ __forceinline__ f32x4 mfma_try(V a, V b, f32x4 c, long) {
  return __builtin_amdgcn_mfma_f32_16x16x32_bf16(
      __builtin_bit_cast(bf16x8, a), __builtin_bit_cast(bf16x8, b), c, 0, 0, 0);
}
__device__ __forceinline__ f32x4 MFMA(short8 a, short8 b, f32x4 c) {
  return mfma_try(a, b, c, 0);
}

// ------------------------------------------------------- canonicalize: x->bf16
__global__ __launch_bounds__(256) void cvt_x_kernel(
    const void* __restrict__ xin, short* __restrict__ xout,
    const unsigned* __restrict__ probe) {
  bool isb = probe_is_bf16(probe);
  size_t i = ((size_t)blockIdx.x * 256 + threadIdx.x) * 8;
  if (isb) {
    *(short8*)&xout[i] = *(const short8*)((const short*)xin + i);
  } else {
    const float* f = (const float*)xin + i;
    float4 a0 = *(const float4*)f;
    float4 a1 = *(const float4*)(f + 4);
    short8 sv;
    sv[0] = f2b(a0.x); sv[1] = f2b(a0.y); sv[2] = f2b(a0.z); sv[3] = f2b(a0.w);
    sv[4] = f2b(a1.x); sv[5] = f2b(a1.y); sv[6] = f2b(a1.z); sv[7] = f2b(a1.w);
    *(short8*)&xout[i] = sv;
  }
}

// ---------------------------------------------------------------- transpose
__global__ __launch_bounds__(256) void transpose_kernel(
    const void* __restrict__ in, short* __restrict__ out, int R, int C,
    const unsigned* __restrict__ probe) {
  bool isb = probe_is_bf16(probe);
  __shared__ float tile[32][33];
  int t = threadIdx.x;
  int bx = blockIdx.x;  // over C
  int by = blockIdx.y;  // over R
  int r = t >> 3, c4 = (t & 7) * 4;
  size_t idx = (size_t)(by * 32 + r) * C + bx * 32 + c4;
  if (isb) {
    short4v v = *(const short4v*)((const short*)in + idx);
    tile[r][c4 + 0] = bf2f(v[0]);
    tile[r][c4 + 1] = bf2f(v[1]);
    tile[r][c4 + 2] = bf2f(v[2]);
    tile[r][c4 + 3] = bf2f(v[3]);
  } else {
    float4 v = *(const float4*)((const float*)in + idx);
    tile[r][c4 + 0] = v.x;
    tile[r][c4 + 1] = v.y;
    tile[r][c4 + 2] = v.z;
    tile[r][c4 + 3] = v.w;
  }
  __syncthreads();
  int rr = t >> 3, k4 = (t & 7) * 4;
  short4v o;
  o[0] = f2b(tile[k4 + 0][rr]);
  o[1] = f2b(tile[k4 + 1][rr]);
  o[2] = f2b(tile[k4 + 2][rr]);
  o[3] = f2b(tile[k4 + 3][rr]);
  *(short4v*)&out[(size_t)(bx * 32 + rr) * R + by * 32 + k4] = o;
}

// ---------------------------------------------------------------- QKV GEMM
// Manual VGPR staging (compiler pipelines the global loads under the MFMA
// phase — r5 evidence) + double-buffered LDS + ONE barrier per K-iter.
__global__ __launch_bounds__(256) void gemm_qkv_kernel(
    const short* __restrict__ X, const short* __restrict__ Wt,
    const void* __restrict__ bias, const unsigned* __restrict__ probe,
    short* __restrict__ Qw, short* __restrict__ Kw, short* __restrict__ Vt) {
  const int K = 1280;
  __shared__ short As[2][128 * 32];
  __shared__ short Bs[2][128 * 32];
  int t = threadIdx.x;
  int bm = blockIdx.x / 30;
  int bn = blockIdx.x % 30;
  int m0 = bm * 128, n0 = bn * 128;
  int w = t >> 6, lane = t & 63;
  int wm = w & 1, wn = w >> 1;
  int quad = lane >> 4, l16 = lane & 15;
  int row = t >> 2, ch = (t & 3) * 8, row2 = row + 64;
  const short* Xr  = X  + (size_t)(m0 + row)  * K + ch;
  const short* Xr2 = X  + (size_t)(m0 + row2) * K + ch;
  const short* Wr  = Wt + (size_t)(n0 + row)  * K + ch;
  const short* Wr2 = Wt + (size_t)(n0 + row2) * K + ch;
  f32x4 acc[4][4] = {};
  short8 a0, a1, b0, b1;
  // prologue: tile 0 -> buf 0
  a0 = *(const short8*)Xr;  a1 = *(const short8*)Xr2;
  b0 = *(const short8*)Wr;  b1 = *(const short8*)Wr2;
  *(short8*)&As[0][row * 32 + ch]  = a0;
  *(short8*)&As[0][row2 * 32 + ch] = a1;
  *(short8*)&Bs[0][row * 32 + ch]  = b0;
  *(short8*)&Bs[0][row2 * 32 + ch] = b1;
  __syncthreads();
  int p = 0;
#define QKV_COMPUTE(pp)                                                       \
  {                                                                           \
    short8 af[4], bfr[4];                                                     \
    _Pragma("unroll") for (int mt = 0; mt < 4; mt++)                          \
        af[mt] = *(const short8*)&As[pp][(wm * 64 + mt * 16 + l16) * 32 + quad * 8]; \
    _Pragma("unroll") for (int nt = 0; nt < 4; nt++)                          \
        bfr[nt] = *(const short8*)&Bs[pp][(wn * 64 + nt * 16 + l16) * 32 + quad * 8]; \
    _Pragma("unroll") for (int mt = 0; mt < 4; mt++)                          \
        _Pragma("unroll") for (int nt = 0; nt < 4; nt++)                      \
            acc[mt][nt] = MFMA(af[mt], bfr[nt], acc[mt][nt]);                 \
  }
  for (int k0 = 32; k0 < K; k0 += 32, p ^= 1) {
    // stage tile k0 into VGPRs (in flight during the MFMA phase below)
    a0 = *(const short8*)(Xr + k0);
    a1 = *(const short8*)(Xr2 + k0);
    b0 = *(const short8*)(Wr + k0);
    b1 = *(const short8*)(Wr2 + k0);
    QKV_COMPUTE(p);
    *(short8*)&As[p ^ 1][row * 32 + ch]  = a0;
    *(short8*)&As[p ^ 1][row2 * 32 + ch] = a1;
    *(short8*)&Bs[p ^ 1][row * 32 + ch]  = b0;
    *(short8*)&Bs[p ^ 1][row2 * 32 + ch] = b1;
    __syncthreads();
  }
  QKV_COMPUTE(p);
  // epilogue: bias (runtime dtype) + scatter
  bool isb = probe_is_bf16(probe);
  float bv[4];
#pragma unroll
  for (int nt = 0; nt < 4; nt++)
    bv[nt] = load_scalar(bias, n0 + wn * 64 + nt * 16 + l16, isb);
#pragma unroll
  for (int mt = 0; mt < 4; mt++) {
    int mbase = m0 + wm * 64 + mt * 16 + quad * 4;
    int b = mbase >> 10, sbase = mbase & 1023;
#pragma unroll
    for (int nt = 0; nt < 4; nt++) {
      int n = n0 + wn * 64 + nt * 16 + l16;
      int which = n / 1280;
      int rmod = n - which * 1280;
      int h = rmod / 80;
      int d = rmod - h * 80;
      int bh = b * 16 + h;
      if (which == 2) {
        short4v vv;
#pragma unroll
        for (int reg = 0; reg < 4; reg++) vv[reg] = f2b(acc[mt][nt][reg] + bv[nt]);
        *(short4v*)&Vt[((size_t)bh * 80 + d) * 1024 + sbase] = vv;
      } else {
        short* dst = (which == 0 ? Qw : Kw);
#pragma unroll
        for (int reg = 0; reg < 4; reg++)
          dst[((size_t)bh * 1024 + sbase + reg) * HDP + d] = f2b(acc[mt][nt][reg] + bv[nt]);
      }
    }
  }
}

// ---------------------------------------------------------------- RoPE
__global__ __launch_bounds__(256) void rope_kernel(
    short* __restrict__ Qw, short* __restrict__ Kw,
    const void* __restrict__ cosb, const void* __restrict__ sinb,
    const unsigned* __restrict__ probe) {
  bool isb = probe_is_bf16(probe);
  int t = threadIdx.x;
  int w = t >> 6, lane = t & 63;
  int job = blockIdx.x * 4 + w;   // 64*1024*2 jobs
  int which = job & 1;
  int row = job >> 1;             // bh*1024 + s
  int s = row & 1023;
  short* ptr = (which ? Kw : Qw) + (size_t)row * HDP;
  if (lane < 40) {
    float p0 = bf2f(ptr[lane]);
    float p1 = bf2f(ptr[lane + 40]);
    float c0 = load_scalar(cosb, s * 80 + lane, isb);
    float s0 = load_scalar(sinb, s * 80 + lane, isb);
    float c1 = load_scalar(cosb, s * 80 + lane + 40, isb);
    float s1 = load_scalar(sinb, s * 80 + lane + 40, isb);
    ptr[lane] = f2b(p0 * c0 - p1 * s0);
    ptr[lane + 40] = f2b(p1 * c1 + p0 * s1);
  } else if (lane < 56) {
    ptr[40 + lane] = 0;  // d = 80..95
  }
}

// ---------------------------------------------------------------- attention
// (unchanged from round 5/6 — staged K/V in LDS + register prefetch pipeline)
__global__ __launch_bounds__(256) void attn_kernel(
    const short* __restrict__ Qw, const short* __restrict__ Kw,
    const short* __restrict__ Vt, short* __restrict__ out) {
  __shared__ short Klds[64 * 104];
  __shared__ short Vlds[80 * 72];
  __shared__ short Ps[4][16 * 72];
  int t = threadIdx.x;
  int w = t >> 6, lane = t & 63;
  int quad = lane >> 4, l16 = lane & 15;
  int bh = blockIdx.x >> 4;
  int qt = blockIdx.x & 15;
  int q0 = qt * 64;
  const short* Kb = Kw + (size_t)bh * 1024 * HDP;
  const short* Vb = Vt + (size_t)bh * 80 * 1024;

  short8 aq[3];
  {
    const short* qrow = Qw + ((size_t)bh * 1024 + q0 + w * 16 + l16) * HDP;
#pragma unroll
    for (int ks = 0; ks < 3; ks++)
      aq[ks] = *(const short8*)&qrow[ks * 32 + quad * 8];
  }

  short8 kreg[3], vreg[3];
#define PREFETCH(c)                                                        \
  {                                                                        \
    _Pragma("unroll") for (int i = 0; i < 3; i++) {                        \
      int idx = i * 256 + t;                                               \
      int row = idx / 12, col = (idx % 12) * 8;                            \
      kreg[i] = *(const short8*)&Kb[(size_t)((c) + row) * HDP + col];      \
    }                                                                      \
    _Pragma("unroll") for (int i = 0; i < 3; i++) {                        \
      int idx = i * 256 + t;                                               \
      if (idx < 640) {                                                     \
        int d = idx >> 3, s0 = (idx & 7) * 8;                              \
        vreg[i] = *(const short8*)&Vb[(size_t)d * 1024 + (c) + s0];        \
      }                                                                    \
    }                                                                      \
  }
#define STORE_LDS()                                                        \
  {                                                                        \
    _Pragma("unroll") for (int i = 0; i < 3; i++) {                        \
      int idx = i * 256 + t;                                               \
      int row = idx / 12, col = (idx % 12) * 8;                            \
      *(short8*)&Klds[row * 104 + col] = kreg[i];                          \
    }                                                                      \
    _Pragma("unroll") for (int i = 0; i < 3; i++) {                        \
      int idx = i * 256 + t;                                               \
      if (idx < 640) {                                                     \
        int d = idx >> 3, s0 = (idx & 7) * 8;                              \
        *(short8*)&Vlds[d * 72 + s0] = vreg[i];                            \
      }                                                                    \
    }                                                                      \
  }

  PREFETCH(0);
  STORE_LDS();
  __syncthreads();

  f32x4 ofr[5] = {};
  float mrow[4], lrow[4];
#pragma unroll
  for (int r = 0; r < 4; r++) { mrow[r] = -INFINITY; lrow[r] = 0.f; }

  for (int c = 0; c < 1024; c += 64) {
    if (c + 64 < 1024) PREFETCH(c + 64);
    f32x4 sf[4] = {};
#pragma unroll
    for (int nt = 0; nt < 4; nt++) {
      short8 bk0 = *(const short8*)&Klds[(nt * 16 + l16) * 104 + 0 * 32 + quad * 8];
      short8 bk1 = *(const short8*)&Klds[(nt * 16 + l16) * 104 + 1 * 32 + quad * 8];
      short8 bk2 = *(const short8*)&Klds[(nt * 16 + l16) * 104 + 2 * 32 + quad * 8];
      sf[nt] = MFMA(aq[0], bk0, sf[nt]);
      sf[nt] = MFMA(aq[1], bk1, sf[nt]);
      sf[nt] = MFMA(aq[2], bk2, sf[nt]);
    }
    float mn[4];
#pragma unroll
    for (int r = 0; r < 4; r++) {
      float mx = -INFINITY;
#pragma unroll
      for (int nt = 0; nt < 4; nt++) {
        sf[nt][r] *= SCALE_F;
        mx = fmaxf(mx, sf[nt][r]);
      }
      mn[r] = mx;
    }
#pragma unroll
    for (int off = 1; off < 16; off <<= 1)
#pragma unroll
      for (int r = 0; r < 4; r++) mn[r] = fmaxf(mn[r], __shfl_xor(mn[r], off));
    float al[4], sum[4];
#pragma unroll
    for (int r = 0; r < 4; r++) {
      float mnew = fmaxf(mrow[r], mn[r]);
      al[r] = __expf(mrow[r] - mnew);
      mrow[r] = mnew;
      float sacc = 0.f;
#pragma unroll
      for (int nt = 0; nt < 4; nt++) {
        float p = __expf(sf[nt][r] - mnew);
        sf[nt][r] = p;
        sacc += p;
      }
      sum[r] = sacc;
    }
#pragma unroll
    for (int off = 1; off < 16; off <<= 1)
#pragma unroll
      for (int r = 0; r < 4; r++) sum[r] += __shfl_xor(sum[r], off);
#pragma unroll
    for (int r = 0; r < 4; r++) lrow[r] = lrow[r] * al[r] + sum[r];
    short* Pw = &Ps[w][0];
#pragma unroll
    for (int nt = 0; nt < 4; nt++)
#pragma unroll
      for (int r = 0; r < 4; r++)
        Pw[(quad * 4 + r) * 72 + nt * 16 + l16] = f2b(sf[nt][r]);
#pragma unroll
    for (int nt = 0; nt < 5; nt++)
#pragma unroll
      for (int r = 0; r < 4; r++) ofr[nt][r] *= al[r];
    __threadfence_block();
    short8 ap[2];
#pragma unroll
    for (int ks = 0; ks < 2; ks++)
      ap[ks] = *(const short8*)&Pw[l16 * 72 + ks * 32 + quad * 8];
#pragma unroll
    for (int nt = 0; nt < 5; nt++) {
      short8 bv0 = *(const short8*)&Vlds[(nt * 16 + l16) * 72 + 0 * 32 + quad * 8];
      short8 bv1 = *(const short8*)&Vlds[(nt * 16 + l16) * 72 + 1 * 32 + quad * 8];
      ofr[nt] = MFMA(ap[0], bv0, ofr[nt]);
      ofr[nt] = MFMA(ap[1], bv1, ofr[nt]);
    }
    __syncthreads();
    if (c + 64 < 1024) {
      STORE_LDS();
      __syncthreads();
    }
  }
  float inv[4];
#pragma unroll
  for (int r = 0; r < 4; r++) inv[r] = 1.f / lrow[r];
  int b = bh >> 4, h = bh & 15;
#pragma unroll
  for (int nt = 0; nt < 5; nt++) {
    int d = nt * 16 + l16;
#pragma unroll
    for (int r = 0; r < 4; r++) {
      int s = q0 + w * 16 + quad * 4 + r;
      out[((size_t)(b * 1024 + s)) * 1280 + h * 80 + d] = f2b(ofr[nt][r] * inv[r]);
    }
  }
}

// ---------------------------------------------------------------- proj GEMM
// Same dbuf manual-staging structure; out(4096x1280 FP32)
__global__ __launch_bounds__(256) void gemm_proj_kernel(
    const short* __restrict__ A, const short* __restrict__ Wt,
    const void* __restrict__ bias, const unsigned* __restrict__ probe,
    float* __restrict__ out) {
  const int K = 1280;
  __shared__ short As[2][128 * 32];
  __shared__ short Bs[2][128 * 32];
  int t = threadIdx.x;
  int bm = blockIdx.x / 10;
  int bn = blockIdx.x % 10;
  int m0 = bm * 128, n0 = bn * 128;
  int w = t >> 6, lane = t & 63;
  int wm = w & 1, wn = w >> 1;
  int quad = lane >> 4, l16 = lane & 15;
  int row = t >> 2, ch = (t & 3) * 8, row2 = row + 64;
  const short* Ar  = A  + (size_t)(m0 + row)  * K + ch;
  const short* Ar2 = A  + (size_t)(m0 + row2) * K + ch;
  const short* Wr  = Wt + (size_t)(n0 + row)  * K + ch;
  const short* Wr2 = Wt + (size_t)(n0 + row2) * K + ch;
  f32x4 acc[4][4] = {};
  short8 a0, a1, b0, b1;
  a0 = *(const short8*)Ar;  a1 = *(const short8*)Ar2;
  b0 = *(const short8*)Wr;  b1 = *(const short8*)Wr2;
  *(short8*)&As[0][row * 32 + ch]  = a0;
  *(short8*)&As[0][row2 * 32 + ch] = a1;
  *(short8*)&Bs[0][row * 32 + ch]  = b0;
  *(short8*)&Bs[0][row2 * 32 + ch] = b1;
  __syncthreads();
  int p = 0;
  for (int k0 = 32; k0 < K; k0 += 32, p ^= 1) {
    a0 = *(const short8*)(Ar + k0);
    a1 = *(const short8*)(Ar2 + k0);
    b0 = *(const short8*)(Wr + k0);
    b1 = *(const short8*)(Wr2 + k0);
    QKV_COMPUTE(p);
    *(short8*)&As[p ^ 1][row * 32 + ch]  = a0;
    *(short8*)&As[p ^ 1][row2 * 32 + ch] = a1;
    *(short8*)&Bs[p ^ 1][row * 32 + ch]  = b0;
    *(short8*)&Bs[p ^ 1][row2 * 32 + ch] = b1;
    __syncthreads();
  }
  QKV_COMPUTE(p);
  bool isb = probe_is_bf16(probe);
  float bv[4];
#pragma unroll
  for (int nt = 0; nt < 4; nt++)
    bv[nt] = load_scalar(bias, n0 + wn * 64 + nt * 16 + l16, isb);
#pragma unroll
  for (int mt = 0; mt < 4; mt++) {
#pragma unroll
    for (int nt = 0; nt < 4; nt++) {
      int n = n0 + wn * 64 + nt * 16 + l16;
#pragma unroll
      for (int reg = 0; reg < 4; reg++) {
        int m = m0 + wm * 64 + mt * 16 + quad * 4 + reg;
        out[(size_t)m * 1280 + n] = acc[mt][nt][reg] + bv[nt];  // FP32 store
      }
    }
  }
}

extern "C" void kernel_launch(void* const* d_in, const int* in_sizes, int n_in,
                              void* d_out, int out_size, void* d_ws, size_t ws_size,
                              hipStream_t stream) {
  const void* x        = d_in[0];
  const void* rope_cos = d_in[1];
  const void* rope_sin = d_in[2];
  const void* Wqkv     = d_in[3];
  const void* bqkv     = d_in[4];
  const void* Wproj    = d_in[5];
  const void* bproj    = d_in[6];
  const unsigned* probe = (const unsigned*)rope_cos;
  char* ws = (char*)d_ws;
  short* Wt1 = (short*)(ws + 0);          // 1280*3840*2 = 9,830,400
  short* Wt2 = (short*)(ws + 9830400);    // 1280*1280*2 = 3,276,800
  short* Qw  = (short*)(ws + 13107200);   // 64*1024*96*2 = 12,582,912
  short* Kw  = (short*)(ws + 25690112);   // 12,582,912
  short* Vt  = (short*)(ws + 38273024);   // 64*1024*80*2 = 10,485,760
  short* Xb  = (short*)(ws + 48758784);   // 4096*1280*2 = 10,485,760
  short* At  = (short*)(ws + 48758784);   // aliases Xb (disjoint lifetimes)

  cvt_x_kernel<<<2560, 256, 0, stream>>>(x, Xb, probe);
  transpose_kernel<<<dim3(3840 / 32, 1280 / 32), 256, 0, stream>>>(Wqkv, Wt1, 1280, 3840, probe);
  transpose_kernel<<<dim3(1280 / 32, 1280 / 32), 256, 0, stream>>>(Wproj, Wt2, 1280, 1280, probe);
  gemm_qkv_kernel<<<32 * 30, 256, 0, stream>>>(Xb, Wt1, bqkv, probe, Qw, Kw, Vt);
  rope_kernel<<<32768, 256, 0, stream>>>(Qw, Kw, rope_cos, rope_sin, probe);
  attn_kernel<<<1024, 256, 0, stream>>>(Qw, Kw, Vt, At);
  gemm_proj_kernel<<<32 * 10, 256, 0, stream>>>(At, Wt2, bproj, probe, (float*)d_out);
}